// Round 2
// baseline (302.255 us; speedup 1.0000x reference)
//
#include <hip/hip_runtime.h>

// MultiViewBEVFusionUnified: project voxel grid into 4 camera feature maps,
// bilinear-sample C=64 channels, mean over valid views.
// dims
#define BB   2
#define NVV  4
#define CC   64
#define HFF  128
#define WFF  232
#define NXB  128
#define NYB  128
#define NZB  8
#define EPSV 1e-5f

// N = NXB*NYB*NZB = 131072 = 2^17 voxels per batch
// thread tid = b*2^17 + x*1024 + y*8 + z  (lanes consecutive in y*8+z)
// out[b][c][x][y][z] flat = ((b*CC + c)*NXB + x)*1024 + (y*8+z)

__global__ __launch_bounds__(256) void bev_fuse_kernel(
    const float* __restrict__ feats,    // [B,NV,C,HF,WF]
    const float* __restrict__ l2c,      // [B,NV,4,4]
    const float* __restrict__ cam2img,  // [B,NV,3,3]
    float* __restrict__ out)            // [B,C,NX,NY,NZ]
{
    const int tid = blockIdx.x * 256 + threadIdx.x;
    const int b   = tid >> 17;
    const int rem = tid & 131071;
    const int xi  = rem >> 10;
    const int yzi = rem & 1023;
    const int yi  = yzi >> 3;
    const int zi  = yzi & 7;

    // voxel center world coords (dx=dy=0.4, dz=0.5)
    const float X = -25.6f + 0.4f * ((float)xi + 0.5f);
    const float Y = -25.6f + 0.4f * ((float)yi + 0.5f);
    const float Z = -1.0f  + 0.5f * ((float)zi + 0.5f);

    float acc[CC];
#pragma unroll
    for (int c = 0; c < CC; ++c) acc[c] = 0.f;
    float cnt = 0.f;

    for (int v = 0; v < NVV; ++v) {
        const float* M = l2c + ((b * NVV + v) << 4);
        const float* K = cam2img + (b * NVV + v) * 9;

        // camera-space point
        const float cx = fmaf(M[0], X, fmaf(M[1], Y, fmaf(M[2],  Z, M[3])));
        const float cy = fmaf(M[4], X, fmaf(M[5], Y, fmaf(M[6],  Z, M[7])));
        const float cz = fmaf(M[8], X, fmaf(M[9], Y, fmaf(M[10], Z, M[11])));

        // image-plane coords
        const float u  = fmaf(K[0], cx, fmaf(K[1], cy, K[2] * cz));
        const float w  = fmaf(K[3], cx, fmaf(K[4], cy, K[5] * cz));

        const float zc   = fmaxf(cz, EPSV);
        const float rz   = 1.f / zc;
        const float px   = u * rz;
        const float py   = w * rz;

        const bool valid = (cz > EPSV) && (px >= 0.f) && (px < (float)WFF)
                         && (py >= 0.f) && (py < (float)HFF);
        if (!valid) continue;
        cnt += 1.f;

        // bilinear (align_corners=False): sample at (px-0.5, py-0.5)
        const float xf  = px - 0.5f, yf = py - 0.5f;
        const float x0f = floorf(xf), y0f = floorf(yf);
        const float wx  = xf - x0f,  wy  = yf - y0f;
        const int x0 = (int)x0f, y0 = (int)y0f;
        const int x1 = x0 + 1,   y1 = y0 + 1;

        const bool bx0 = (x0 >= 0) & (x0 < WFF);
        const bool bx1 = (x1 >= 0) & (x1 < WFF);
        const bool by0 = (y0 >= 0) & (y0 < HFF);
        const bool by1 = (y1 >= 0) & (y1 < HFF);

        // fold OOB masks into the weights; clamped indices stay in-bounds
        const float w00 = (bx0 && by0) ? (1.f - wx) * (1.f - wy) : 0.f;
        const float w01 = (bx1 && by0) ? wx * (1.f - wy)         : 0.f;
        const float w10 = (bx0 && by1) ? (1.f - wx) * wy         : 0.f;
        const float w11 = (bx1 && by1) ? wx * wy                 : 0.f;

        const int x0c = min(max(x0, 0), WFF - 1);
        const int x1c = min(max(x1, 0), WFF - 1);
        const int y0c = min(max(y0, 0), HFF - 1);
        const int y1c = min(max(y1, 0), HFF - 1);

        const int o00 = y0c * WFF + x0c;
        const int o01 = y0c * WFF + x1c;
        const int o10 = y1c * WFF + x0c;
        const int o11 = y1c * WFF + x1c;

        const float* fb = feats + (size_t)(b * NVV + v) * (CC * HFF * WFF);

#pragma unroll 8
        for (int c = 0; c < CC; ++c) {
            const float* fc = fb + c * (HFF * WFF);
            float a = acc[c];
            a = fmaf(fc[o00], w00, a);
            a = fmaf(fc[o01], w01, a);
            a = fmaf(fc[o10], w10, a);
            a = fmaf(fc[o11], w11, a);
            acc[c] = a;
        }
    }

    const float scale = 1.f / fmaxf(cnt, 1.f);
    float* ob = out + (size_t)b * CC * 131072 + xi * 1024 + yzi;
#pragma unroll 8
    for (int c = 0; c < CC; ++c)
        ob[(size_t)c * 131072] = acc[c] * scale;
}

extern "C" void kernel_launch(void* const* d_in, const int* in_sizes, int n_in,
                              void* d_out, int out_size, void* d_ws, size_t ws_size,
                              hipStream_t stream) {
    const float* feats   = (const float*)d_in[0];
    const float* l2c     = (const float*)d_in[1];
    const float* cam2img = (const float*)d_in[2];
    float* out           = (float*)d_out;

    // B*NX*NY*NZ = 262144 threads, 256/block -> 1024 blocks
    bev_fuse_kernel<<<1024, 256, 0, stream>>>(feats, l2c, cam2img, out);
}

// Round 4
// 192.711 us; speedup vs baseline: 1.5684x; 1.5684x over previous
//
#include <hip/hip_runtime.h>

// MultiViewBEVFusionUnified: project voxel grid into 4 camera feature maps,
// bilinear-sample C=64 channels, mean over valid views.
#define BB   2
#define NVV  4
#define CC   64
#define CG   16            // channels per thread (CC/CG channel groups in gridDim.y)
#define HFF  128
#define WFF  232
#define NXB  128
#define NYB  128
#define NZB  8
#define EPSV 1e-5f

// N = NXB*NYB*NZB = 131072 = 2^17 voxels per batch
// thread: blockIdx.x*256+tid over B*2^17 voxels (lanes consecutive in y*8+z)
// blockIdx.y = channel group (4 groups of 16)
// out[b][c][x][y][z] flat = ((b*CC + c)*NXB + x)*1024 + (y*8+z)

__global__ __launch_bounds__(256) void bev_fuse_kernel(
    const float* __restrict__ feats,    // [B,NV,C,HF,WF]
    const float* __restrict__ l2c,      // [B,NV,4,4]
    const float* __restrict__ cam2img,  // [B,NV,3,3]
    float* __restrict__ out)            // [B,C,NX,NY,NZ]
{
    const int tid = blockIdx.x * 256 + threadIdx.x;
    const int b   = tid >> 17;
    const int rem = tid & 131071;
    const int xi  = rem >> 10;
    const int yzi = rem & 1023;
    const int yi  = yzi >> 3;
    const int zi  = yzi & 7;
    const int c0  = blockIdx.y * CG;

    // voxel center world coords (dx=dy=0.4, dz=0.5)
    const float X = -25.6f + 0.4f * ((float)xi + 0.5f);
    const float Y = -25.6f + 0.4f * ((float)yi + 0.5f);
    const float Z = -1.0f  + 0.5f * ((float)zi + 0.5f);

    float acc[CG];
#pragma unroll
    for (int c = 0; c < CG; ++c) acc[c] = 0.f;
    float cnt = 0.f;

    for (int v = 0; v < NVV; ++v) {
        const float* M = l2c + ((b * NVV + v) << 4);
        const float* K = cam2img + (b * NVV + v) * 9;

        // camera-space point
        const float cx = fmaf(M[0], X, fmaf(M[1], Y, fmaf(M[2],  Z, M[3])));
        const float cy = fmaf(M[4], X, fmaf(M[5], Y, fmaf(M[6],  Z, M[7])));
        const float cz = fmaf(M[8], X, fmaf(M[9], Y, fmaf(M[10], Z, M[11])));

        // image-plane coords
        const float u = fmaf(K[0], cx, fmaf(K[1], cy, K[2] * cz));
        const float w = fmaf(K[3], cx, fmaf(K[4], cy, K[5] * cz));

        const float zc = fmaxf(cz, EPSV);
        const float rz = 1.f / zc;
        const float px = u * rz;
        const float py = w * rz;

        const bool valid = (cz > EPSV) && (px >= 0.f) && (px < (float)WFF)
                         && (py >= 0.f) && (py < (float)HFF);
        if (!valid) continue;
        cnt += 1.f;

        // bilinear (align_corners=False): sample at (px-0.5, py-0.5)
        const float xf  = px - 0.5f, yf = py - 0.5f;
        const float x0f = floorf(xf), y0f = floorf(yf);
        const float wx  = xf - x0f,  wy  = yf - y0f;
        const int x0 = (int)x0f, y0 = (int)y0f;
        const int x1 = x0 + 1,   y1 = y0 + 1;

        const bool bx0 = (x0 >= 0) & (x0 < WFF);
        const bool bx1 = (x1 >= 0) & (x1 < WFF);
        const bool by0 = (y0 >= 0) & (y0 < HFF);
        const bool by1 = (y1 >= 0) & (y1 < HFF);

        // fold OOB masks into the weights; clamped indices stay in-bounds
        const float w00 = (bx0 && by0) ? (1.f - wx) * (1.f - wy) : 0.f;
        const float w01 = (bx1 && by0) ? wx * (1.f - wy)         : 0.f;
        const float w10 = (bx0 && by1) ? (1.f - wx) * wy         : 0.f;
        const float w11 = (bx1 && by1) ? wx * wy                 : 0.f;

        const int x0c = min(max(x0, 0), WFF - 1);
        const int x1c = min(max(x1, 0), WFF - 1);
        const int y0c = min(max(y0, 0), HFF - 1);
        const int y1c = min(max(y1, 0), HFF - 1);

        const int o00 = y0c * WFF + x0c;
        const int o01 = y0c * WFF + x1c;
        const int o10 = y1c * WFF + x0c;
        const int o11 = y1c * WFF + x1c;

        const float* fb = feats + (size_t)(b * NVV + v) * (CC * HFF * WFF)
                                + (size_t)c0 * (HFF * WFF);

#pragma unroll
        for (int c = 0; c < CG; ++c) {
            const float* fc = fb + c * (HFF * WFF);
            float a = acc[c];
            a = fmaf(fc[o00], w00, a);
            a = fmaf(fc[o01], w01, a);
            a = fmaf(fc[o10], w10, a);
            a = fmaf(fc[o11], w11, a);
            acc[c] = a;
        }
    }

    const float scale = 1.f / fmaxf(cnt, 1.f);
    float* ob = out + (size_t)b * CC * 131072 + (size_t)c0 * 131072 + xi * 1024 + yzi;
#pragma unroll
    for (int c = 0; c < CG; ++c)
        ob[(size_t)c * 131072] = acc[c] * scale;
}

extern "C" void kernel_launch(void* const* d_in, const int* in_sizes, int n_in,
                              void* d_out, int out_size, void* d_ws, size_t ws_size,
                              hipStream_t stream) {
    const float* feats   = (const float*)d_in[0];
    const float* l2c     = (const float*)d_in[1];
    const float* cam2img = (const float*)d_in[2];
    float* out           = (float*)d_out;

    // voxels: B*2^17 / 256 = 1024 blocks; channel groups: CC/CG = 4
    dim3 grid(1024, CC / CG, 1);
    bev_fuse_kernel<<<grid, 256, 0, stream>>>(feats, l2c, cam2img, out);
}

// Round 5
// 146.655 us; speedup vs baseline: 2.0610x; 1.3140x over previous
//
#include <hip/hip_runtime.h>

// MultiViewBEVFusionUnified — two-kernel plan:
//  A) transpose feats [8][C=64][HW] -> ws [8][HW][C]  (channel-last)
//  B) per block: 64 voxels; phase1 = 64 vox x 4 views projections -> LDS;
//     phase2 = wave-per-16-voxels, lane=channel, coalesced 256B corner loads;
//     LDS transpose -> coalesced output stores.
#define BB   2
#define NVV  4
#define CC   64
#define HFF  128
#define WFF  232
#define HW   (HFF*WFF)        // 29696
#define EPSV 1e-5f

// ---------------- Kernel A: channel-last transpose ----------------
__global__ __launch_bounds__(256) void transpose_kernel(
    const float* __restrict__ feats, float* __restrict__ ft)
{
    __shared__ float lds[64][65];
    const int t   = threadIdx.x;
    const int hw0 = blockIdx.x * 64;
    const size_t sbase = (size_t)blockIdx.y * (CC * HW);

    const int lhw = t & 63, crow = t >> 6;
#pragma unroll
    for (int r = 0; r < 16; ++r) {
        const int c = crow * 16 + r;
        lds[c][lhw] = feats[sbase + (size_t)c * HW + hw0 + lhw];
    }
    __syncthreads();
    const int lc = t & 63, hrow = t >> 6;
#pragma unroll
    for (int r = 0; r < 16; ++r) {
        const int hw = hrow + 4 * r;
        ft[sbase + (size_t)(hw0 + hw) * CC + lc] = lds[lc][hw];
    }
}

// ---------------- Kernel B: project + gather + fuse ----------------
__global__ __launch_bounds__(256) void bev_sample_kernel(
    const float* __restrict__ ft,       // [8][HW][64] channel-last
    const float* __restrict__ l2c,      // [B,NV,4,4]
    const float* __restrict__ cam2img,  // [B,NV,3,3]
    float* __restrict__ out)            // [B,C,NX,NY,NZ]
{
    __shared__ __align__(16) char smem[16640];
    int4*   s_off = (int4*)smem;             // [4][64] corner pixel indices
    float4* s_w   = (float4*)(smem + 4096);  // [4][64] bilinear weights
    int*    s_fl  = (int*)(smem + 8192);     // [64] packed valid bytes
    float*  s_t   = (float*)smem;            // [64][65] reuse for out transpose

    const int t   = threadIdx.x;
    const int bid = blockIdx.x;
    const int b   = bid >> 11;
    const int rem = bid & 2047;
    const int xi  = rem >> 4;
    const int yz0 = (rem & 15) << 6;

    // ---- phase 1: projections; thread = (view v = t>>6, voxel j = t&63)
    {
        const int v = t >> 6, j = t & 63;
        const int yzi = yz0 + j;
        const int yi = yzi >> 3, zi = yzi & 7;
        const float X = -25.6f + 0.4f * ((float)xi + 0.5f);
        const float Y = -25.6f + 0.4f * ((float)yi + 0.5f);
        const float Z = -1.0f  + 0.5f * ((float)zi + 0.5f);

        const float* M = l2c + ((b * NVV + v) << 4);
        const float* K = cam2img + (b * NVV + v) * 9;
        const float cx = fmaf(M[0], X, fmaf(M[1], Y, fmaf(M[2],  Z, M[3])));
        const float cy = fmaf(M[4], X, fmaf(M[5], Y, fmaf(M[6],  Z, M[7])));
        const float cz = fmaf(M[8], X, fmaf(M[9], Y, fmaf(M[10], Z, M[11])));
        const float u = fmaf(K[0], cx, fmaf(K[1], cy, K[2] * cz));
        const float w = fmaf(K[3], cx, fmaf(K[4], cy, K[5] * cz));
        const float zc = fmaxf(cz, EPSV);
        const float rz = 1.f / zc;
        const float px = u * rz, py = w * rz;

        const bool valid = (cz > EPSV) && (px >= 0.f) && (px < (float)WFF)
                         && (py >= 0.f) && (py < (float)HFF);

        const float xf = px - 0.5f, yf = py - 0.5f;
        const float x0f = floorf(xf), y0f = floorf(yf);
        const float wx = xf - x0f, wy = yf - y0f;
        const int x0 = (int)x0f, y0 = (int)y0f;
        const int x1 = x0 + 1, y1 = y0 + 1;
        const bool bx0 = (x0 >= 0) & (x0 < WFF);
        const bool bx1 = (x1 >= 0) & (x1 < WFF);
        const bool by0 = (y0 >= 0) & (y0 < HFF);
        const bool by1 = (y1 >= 0) & (y1 < HFF);
        float4 wt;
        wt.x = (bx0 && by0) ? (1.f - wx) * (1.f - wy) : 0.f;
        wt.y = (bx1 && by0) ? wx * (1.f - wy)         : 0.f;
        wt.z = (bx0 && by1) ? (1.f - wx) * wy         : 0.f;
        wt.w = (bx1 && by1) ? wx * wy                 : 0.f;
        const int x0c = min(max(x0, 0), WFF-1), x1c = min(max(x1, 0), WFF-1);
        const int y0c = min(max(y0, 0), HFF-1), y1c = min(max(y1, 0), HFF-1);
        int4 off;
        off.x = y0c*WFF + x0c; off.y = y0c*WFF + x1c;
        off.z = y1c*WFF + x0c; off.w = y1c*WFF + x1c;

        s_off[v*64 + j] = off;
        s_w  [v*64 + j] = wt;
        ((char*)(smem + 8192))[j*4 + v] = valid ? 1 : 0;
    }
    __syncthreads();

    // ---- phase 2: gather; wave wv owns voxels wv*16..wv*16+15, lane = channel
    const int wv = t >> 6, c = t & 63;
    float acc[16];
#pragma unroll
    for (int k = 0; k < 16; ++k) acc[k] = 0.f;

    const float* fslice0 = ft + (size_t)(b * NVV) * (HW * CC);
#pragma unroll
    for (int k = 0; k < 16; ++k) {
        const int j = wv*16 + k;
        const int flags = s_fl[j];                       // broadcast read
        const int cnt = (flags & 1) + ((flags >> 8) & 1)
                      + ((flags >> 16) & 1) + ((flags >> 24) & 1);
        float a = 0.f;
#pragma unroll
        for (int v = 0; v < NVV; ++v) {
            if ((flags >> (8*v)) & 1) {                  // wave-uniform branch
                const int4   off = s_off[v*64 + j];      // broadcast
                const float4 wt  = s_w  [v*64 + j];      // broadcast
                const float* fb  = fslice0 + (size_t)v * (HW * CC);
                a = fmaf(fb[(size_t)off.x*CC + c], wt.x, a);   // 256B coalesced
                a = fmaf(fb[(size_t)off.y*CC + c], wt.y, a);
                a = fmaf(fb[(size_t)off.z*CC + c], wt.z, a);
                a = fmaf(fb[(size_t)off.w*CC + c], wt.w, a);
            }
        }
        const float scale = (cnt <= 1) ? 1.f : (cnt == 2) ? 0.5f
                          : (cnt == 3) ? (1.f/3.f) : 0.25f;
        acc[k] = a * scale;
    }
    __syncthreads();   // phase-2 LDS reads done before aliasing s_t

    // ---- LDS transpose: s_t[voxel][channel]
#pragma unroll
    for (int k = 0; k < 16; ++k)
        s_t[(wv*16 + k)*65 + c] = acc[k];
    __syncthreads();

    // ---- coalesced output: lane = voxel, loop channels
    const int jv = t & 63, cr = t >> 6;
    float* ob = out + (size_t)b * (CC * 131072) + (size_t)xi * 1024 + yz0;
#pragma unroll
    for (int r = 0; r < 16; ++r) {
        const int c2 = cr + 4*r;
        ob[(size_t)c2 * 131072 + jv] = s_t[jv*65 + c2];
    }
}

// ---------------- Fallback (round-4 kernel) if ws too small ----------------
#define CG 16
__global__ __launch_bounds__(256) void bev_fuse_kernel(
    const float* __restrict__ feats, const float* __restrict__ l2c,
    const float* __restrict__ cam2img, float* __restrict__ out)
{
    const int tid = blockIdx.x * 256 + threadIdx.x;
    const int b   = tid >> 17;
    const int rem = tid & 131071;
    const int xi  = rem >> 10;
    const int yzi = rem & 1023;
    const int yi  = yzi >> 3;
    const int zi  = yzi & 7;
    const int c0  = blockIdx.y * CG;

    const float X = -25.6f + 0.4f * ((float)xi + 0.5f);
    const float Y = -25.6f + 0.4f * ((float)yi + 0.5f);
    const float Z = -1.0f  + 0.5f * ((float)zi + 0.5f);

    float acc[CG];
#pragma unroll
    for (int c = 0; c < CG; ++c) acc[c] = 0.f;
    float cnt = 0.f;

    for (int v = 0; v < NVV; ++v) {
        const float* M = l2c + ((b * NVV + v) << 4);
        const float* K = cam2img + (b * NVV + v) * 9;
        const float cx = fmaf(M[0], X, fmaf(M[1], Y, fmaf(M[2],  Z, M[3])));
        const float cy = fmaf(M[4], X, fmaf(M[5], Y, fmaf(M[6],  Z, M[7])));
        const float cz = fmaf(M[8], X, fmaf(M[9], Y, fmaf(M[10], Z, M[11])));
        const float u = fmaf(K[0], cx, fmaf(K[1], cy, K[2] * cz));
        const float w = fmaf(K[3], cx, fmaf(K[4], cy, K[5] * cz));
        const float zc = fmaxf(cz, EPSV);
        const float rz = 1.f / zc;
        const float px = u * rz, py = w * rz;
        const bool valid = (cz > EPSV) && (px >= 0.f) && (px < (float)WFF)
                         && (py >= 0.f) && (py < (float)HFF);
        if (!valid) continue;
        cnt += 1.f;
        const float xf = px - 0.5f, yf = py - 0.5f;
        const float x0f = floorf(xf), y0f = floorf(yf);
        const float wx = xf - x0f, wy = yf - y0f;
        const int x0 = (int)x0f, y0 = (int)y0f;
        const int x1 = x0 + 1, y1 = y0 + 1;
        const bool bx0 = (x0 >= 0) & (x0 < WFF);
        const bool bx1 = (x1 >= 0) & (x1 < WFF);
        const bool by0 = (y0 >= 0) & (y0 < HFF);
        const bool by1 = (y1 >= 0) & (y1 < HFF);
        const float w00 = (bx0 && by0) ? (1.f - wx) * (1.f - wy) : 0.f;
        const float w01 = (bx1 && by0) ? wx * (1.f - wy)         : 0.f;
        const float w10 = (bx0 && by1) ? (1.f - wx) * wy         : 0.f;
        const float w11 = (bx1 && by1) ? wx * wy                 : 0.f;
        const int x0c = min(max(x0,0),WFF-1), x1c = min(max(x1,0),WFF-1);
        const int y0c = min(max(y0,0),HFF-1), y1c = min(max(y1,0),HFF-1);
        const int o00 = y0c*WFF+x0c, o01 = y0c*WFF+x1c;
        const int o10 = y1c*WFF+x0c, o11 = y1c*WFF+x1c;
        const float* fb = feats + (size_t)(b*NVV+v)*(CC*HW) + (size_t)c0*HW;
#pragma unroll
        for (int c = 0; c < CG; ++c) {
            const float* fc = fb + c * HW;
            float a = acc[c];
            a = fmaf(fc[o00], w00, a);
            a = fmaf(fc[o01], w01, a);
            a = fmaf(fc[o10], w10, a);
            a = fmaf(fc[o11], w11, a);
            acc[c] = a;
        }
    }
    const float scale = 1.f / fmaxf(cnt, 1.f);
    float* ob = out + (size_t)b*(CC*131072) + (size_t)c0*131072 + xi*1024 + yzi;
#pragma unroll
    for (int c = 0; c < CG; ++c)
        ob[(size_t)c * 131072] = acc[c] * scale;
}

extern "C" void kernel_launch(void* const* d_in, const int* in_sizes, int n_in,
                              void* d_out, int out_size, void* d_ws, size_t ws_size,
                              hipStream_t stream) {
    const float* feats   = (const float*)d_in[0];
    const float* l2c     = (const float*)d_in[1];
    const float* cam2img = (const float*)d_in[2];
    float* out           = (float*)d_out;

    const size_t need = (size_t)BB * NVV * HW * CC * sizeof(float);  // 60.8 MB
    if (ws_size >= need) {
        float* ft = (float*)d_ws;
        dim3 gA(HW / 64, BB * NVV, 1);                 // 464 x 8
        transpose_kernel<<<gA, 256, 0, stream>>>(feats, ft);
        bev_sample_kernel<<<4096, 256, 0, stream>>>(ft, l2c, cam2img, out);
    } else {
        dim3 grid(1024, CC / CG, 1);
        bev_fuse_kernel<<<grid, 256, 0, stream>>>(feats, l2c, cam2img, out);
    }
}

// Round 8
// 143.479 us; speedup vs baseline: 2.1066x; 1.0221x over previous
//
#include <hip/hip_runtime.h>

// MultiViewBEVFusionUnified — two-kernel plan:
//  A) transpose feats [8][C=64][HW] -> ws [8][HW][C] (channel-last), float4 global IO
//  B) per block: 64 voxels; phase1 = 64 vox x 4 views projections -> LDS;
//     phase2 = wave-per-16-voxels, lane covers (channel-pair, corner-half),
//     paired-corner dwordx2 gathers (512B/wave); shfl_xor(32) combine;
//     LDS transpose -> coalesced output stores.
#define BB   2
#define NVV  4
#define CC   64
#define HFF  128
#define WFF  232
#define HW   (HFF*WFF)        // 29696
#define EPSV 1e-5f

// ---------------- Kernel A: channel-last transpose (float4 IO) ----------------
__global__ __launch_bounds__(256) void transpose_kernel(
    const float* __restrict__ feats, float* __restrict__ ft)
{
    __shared__ float lds[64][65];
    const int t   = threadIdx.x;
    const int hw0 = blockIdx.x * 64;
    const size_t sbase = (size_t)blockIdx.y * (CC * HW);
    const int l16 = t & 15, g16 = t >> 4;

    // load: c = g16 + 16r, hw = 4*l16 .. +3 (wave: 4x256B contiguous segments)
#pragma unroll
    for (int r = 0; r < 4; ++r) {
        const int c = g16 + 16 * r;
        const float4 v = *(const float4*)(feats + sbase + (size_t)c * HW + hw0 + 4 * l16);
        lds[c][4*l16 + 0] = v.x;
        lds[c][4*l16 + 1] = v.y;
        lds[c][4*l16 + 2] = v.z;
        lds[c][4*l16 + 3] = v.w;
    }
    __syncthreads();
    // store: c4 = 4*l16, hw = g16 + 16r (wave writes 1KB contiguous)
#pragma unroll
    for (int r = 0; r < 4; ++r) {
        const int hw = g16 + 16 * r;
        float4 v;
        v.x = lds[4*l16 + 0][hw];
        v.y = lds[4*l16 + 1][hw];
        v.z = lds[4*l16 + 2][hw];
        v.w = lds[4*l16 + 3][hw];
        *(float4*)(ft + sbase + (size_t)(hw0 + hw) * CC + 4 * l16) = v;
    }
}

// ---------------- Kernel B: project + paired-corner gather + fuse ----------------
__global__ __launch_bounds__(256) void bev_sample_kernel(
    const float* __restrict__ ft,       // [8][HW][64] channel-last
    const float* __restrict__ l2c,      // [B,NV,4,4]
    const float* __restrict__ cam2img,  // [B,NV,3,3]
    float* __restrict__ out)            // [B,C,NX,NY,NZ]
{
    __shared__ __align__(16) char smem[64 * 66 * 4];   // 16896 B
    float4* s_w   = (float4*)smem;                 // [4][64] pair weights (4KB)
    int2*   s_off = (int2*)(smem + 4096);          // [4][64] row offsets  (2KB)
    int*    s_fl  = (int*)(smem + 6144);           // [64] packed valid bytes
    float*  s_t   = (float*)smem;                  // [64][66] out transpose (aliases)

    const int t   = threadIdx.x;
    const int bid = blockIdx.x;
    const int b   = bid >> 11;
    const int rem = bid & 2047;
    const int xi  = rem >> 4;
    const int yz0 = (rem & 15) << 6;

    // ---- phase 1: projections; thread = (view v = t>>6, voxel j = t&63)
    {
        const int v = t >> 6, j = t & 63;
        const int yzi = yz0 + j;
        const int yi = yzi >> 3, zi = yzi & 7;
        const float X = -25.6f + 0.4f * ((float)xi + 0.5f);
        const float Y = -25.6f + 0.4f * ((float)yi + 0.5f);
        const float Z = -1.0f  + 0.5f * ((float)zi + 0.5f);

        const float* M = l2c + ((b * NVV + v) << 4);
        const float* K = cam2img + (b * NVV + v) * 9;
        const float cx = fmaf(M[0], X, fmaf(M[1], Y, fmaf(M[2],  Z, M[3])));
        const float cy = fmaf(M[4], X, fmaf(M[5], Y, fmaf(M[6],  Z, M[7])));
        const float cz = fmaf(M[8], X, fmaf(M[9], Y, fmaf(M[10], Z, M[11])));
        const float u = fmaf(K[0], cx, fmaf(K[1], cy, K[2] * cz));
        const float w = fmaf(K[3], cx, fmaf(K[4], cy, K[5] * cz));
        const float zc = fmaxf(cz, EPSV);
        const float rz = 1.f / zc;
        const float px = u * rz, py = w * rz;

        const bool valid = (cz > EPSV) && (px >= 0.f) && (px < (float)WFF)
                         && (py >= 0.f) && (py < (float)HFF);

        // bilinear (align_corners=False): sample at (px-0.5, py-0.5)
        const float xf = px - 0.5f, yf = py - 0.5f;
        const float x0f = floorf(xf), y0f = floorf(yf);
        const float wx = xf - x0f, wy = yf - y0f;
        const int x0 = (int)x0f, y0 = (int)y0f;   // valid => x0 in [-1,231], y0 in [-1,127]
        const int y1 = y0 + 1;

        // pair base bx: loaded pixels are (bx, bx+1); remap corner weights onto them
        const int bx = min(max(x0, 0), WFF - 2);
        float wLx, wHx;
        if (x0 < 0)            { wLx = wx;       wHx = 0.f; }       // corner1 at x=0 is L
        else if (x0 >= WFF-1)  { wLx = 0.f;      wHx = 1.f - wx; }  // corner0 at x=231 is H
        else                   { wLx = 1.f - wx; wHx = wx; }

        const float ay0 = (y0 >= 0)      ? (1.f - wy) : 0.f;
        const float ay1 = (y1 <= HFF-1)  ? wy         : 0.f;
        const int y0c = max(y0, 0);
        const int y1c = min(y1, HFF - 1);

        float4 wt;
        wt.x = wLx * ay0; wt.y = wHx * ay0;   // row y0: (L,H)
        wt.z = wLx * ay1; wt.w = wHx * ay1;   // row y1: (L,H)
        int2 off;
        off.x = y0c * WFF + bx;
        off.y = y1c * WFF + bx;

        s_w  [v*64 + j] = wt;
        s_off[v*64 + j] = off;
        ((char*)(smem + 6144))[j*4 + v] = valid ? 1 : 0;
    }
    __syncthreads();

    // ---- phase 2: gather; wave wv owns voxels wv*16..+15
    // lane l<32: pixel L, channels {2l,2l+1}; lane l>=32: pixel H, channels {2(l-32),..}
    const int wv = t >> 6, lane = t & 63;
    const int half = lane >> 5;
    float2 acc[16];
#pragma unroll
    for (int k = 0; k < 16; ++k) acc[k] = make_float2(0.f, 0.f);

    const float* fsl = ft + (size_t)(b * NVV) * (HW * CC);
#pragma unroll
    for (int k = 0; k < 16; ++k) {
        const int j = wv*16 + k;
        const int flags = s_fl[j];                       // broadcast
        if (flags) {                                     // wave-uniform
            const int cnt = (flags & 1) + ((flags >> 8) & 1)
                          + ((flags >> 16) & 1) + ((flags >> 24) & 1);
            float ax = 0.f, ay = 0.f;
#pragma unroll
            for (int v = 0; v < NVV; ++v) {
                if ((flags >> (8*v)) & 1) {              // wave-uniform
                    const int2   off = s_off[v*64 + j];  // broadcast
                    const float4 wt  = s_w  [v*64 + j];  // broadcast
                    const float* p0  = fsl + (size_t)v * (HW * CC);
                    // 512B pair loads: rows off.x / off.y, 128 floats each
                    const float2 f0 = *(const float2*)(p0 + (size_t)off.x * CC + 2*lane);
                    const float2 f1 = *(const float2*)(p0 + (size_t)off.y * CC + 2*lane);
                    const float wa = half ? wt.y : wt.x;
                    const float wb = half ? wt.w : wt.z;
                    ax = fmaf(f0.x, wa, ax); ay = fmaf(f0.y, wa, ay);
                    ax = fmaf(f1.x, wb, ax); ay = fmaf(f1.y, wb, ay);
                }
            }
            const float scale = (cnt <= 1) ? 1.f : (cnt == 2) ? 0.5f
                              : (cnt == 3) ? (1.f/3.f) : 0.25f;
            acc[k].x = ax * scale;
            acc[k].y = ay * scale;
        }
    }
    __syncthreads();   // phase-2 LDS reads done before aliasing s_t

    // ---- combine corner halves, write transposed to LDS
    const int m2 = (lane & 31) * 2;
#pragma unroll
    for (int k = 0; k < 16; ++k) {
        const float sx = acc[k].x + __shfl_xor(acc[k].x, 32);
        const float sy = acc[k].y + __shfl_xor(acc[k].y, 32);
        if ((k >> 3) == half) {   // half0 writes k=0..7, half1 writes k=8..15
            float2* dst = (float2*)&s_t[(wv*16 + k)*66 + m2];
            *dst = make_float2(sx, sy);
        }
    }
    __syncthreads();

    // ---- coalesced output: lane = voxel, loop channels
    const int jv = t & 63, cr = t >> 6;
    float* ob = out + (size_t)b * (CC * 131072) + (size_t)xi * 1024 + yz0;
#pragma unroll
    for (int r = 0; r < 16; ++r) {
        const int c2 = cr + 4*r;
        ob[(size_t)c2 * 131072 + jv] = s_t[jv*66 + c2];
    }
}

// ---------------- Fallback (round-4 kernel) if ws too small ----------------
#define CG 16
__global__ __launch_bounds__(256) void bev_fuse_kernel(
    const float* __restrict__ feats, const float* __restrict__ l2c,
    const float* __restrict__ cam2img, float* __restrict__ out)
{
    const int tid = blockIdx.x * 256 + threadIdx.x;
    const int b   = tid >> 17;
    const int rem = tid & 131071;
    const int xi  = rem >> 10;
    const int yzi = rem & 1023;
    const int yi  = yzi >> 3;
    const int zi  = yzi & 7;
    const int c0  = blockIdx.y * CG;

    const float X = -25.6f + 0.4f * ((float)xi + 0.5f);
    const float Y = -25.6f + 0.4f * ((float)yi + 0.5f);
    const float Z = -1.0f  + 0.5f * ((float)zi + 0.5f);

    float acc[CG];
#pragma unroll
    for (int c = 0; c < CG; ++c) acc[c] = 0.f;
    float cnt = 0.f;

    for (int v = 0; v < NVV; ++v) {
        const float* M = l2c + ((b * NVV + v) << 4);
        const float* K = cam2img + (b * NVV + v) * 9;
        const float cx = fmaf(M[0], X, fmaf(M[1], Y, fmaf(M[2],  Z, M[3])));
        const float cy = fmaf(M[4], X, fmaf(M[5], Y, fmaf(M[6],  Z, M[7])));
        const float cz = fmaf(M[8], X, fmaf(M[9], Y, fmaf(M[10], Z, M[11])));
        const float u = fmaf(K[0], cx, fmaf(K[1], cy, K[2] * cz));
        const float w = fmaf(K[3], cx, fmaf(K[4], cy, K[5] * cz));
        const float zc = fmaxf(cz, EPSV);
        const float rz = 1.f / zc;
        const float px = u * rz, py = w * rz;
        const bool valid = (cz > EPSV) && (px >= 0.f) && (px < (float)WFF)
                         && (py >= 0.f) && (py < (float)HFF);
        if (!valid) continue;
        cnt += 1.f;
        const float xf = px - 0.5f, yf = py - 0.5f;
        const float x0f = floorf(xf), y0f = floorf(yf);
        const float wx = xf - x0f, wy = yf - y0f;
        const int x0 = (int)x0f, y0 = (int)y0f;
        const int x1 = x0 + 1, y1 = y0 + 1;
        const bool bx0 = (x0 >= 0) & (x0 < WFF);
        const bool bx1 = (x1 >= 0) & (x1 < WFF);
        const bool by0 = (y0 >= 0) & (y0 < HFF);
        const bool by1 = (y1 >= 0) & (y1 < HFF);
        const float w00 = (bx0 && by0) ? (1.f - wx) * (1.f - wy) : 0.f;
        const float w01 = (bx1 && by0) ? wx * (1.f - wy)         : 0.f;
        const float w10 = (bx0 && by1) ? (1.f - wx) * wy         : 0.f;
        const float w11 = (bx1 && by1) ? wx * wy                 : 0.f;
        const int x0c = min(max(x0,0),WFF-1), x1c = min(max(x1,0),WFF-1);
        const int y0c = min(max(y0,0),HFF-1), y1c = min(max(y1,0),HFF-1);
        const int o00 = y0c*WFF+x0c, o01 = y0c*WFF+x1c;
        const int o10 = y1c*WFF+x0c, o11 = y1c*WFF+x1c;
        const float* fb = feats + (size_t)(b*NVV+v)*(CC*HW) + (size_t)c0*HW;
#pragma unroll
        for (int c = 0; c < CG; ++c) {
            const float* fc = fb + c * HW;
            float a = acc[c];
            a = fmaf(fc[o00], w00, a);
            a = fmaf(fc[o01], w01, a);
            a = fmaf(fc[o10], w10, a);
            a = fmaf(fc[o11], w11, a);
            acc[c] = a;
        }
    }
    const float scale = 1.f / fmaxf(cnt, 1.f);
    float* ob = out + (size_t)b*(CC*131072) + (size_t)c0*131072 + xi*1024 + yzi;
#pragma unroll
    for (int c = 0; c < CG; ++c)
        ob[(size_t)c * 131072] = acc[c] * scale;
}

extern "C" void kernel_launch(void* const* d_in, const int* in_sizes, int n_in,
                              void* d_out, int out_size, void* d_ws, size_t ws_size,
                              hipStream_t stream) {
    const float* feats   = (const float*)d_in[0];
    const float* l2c     = (const float*)d_in[1];
    const float* cam2img = (const float*)d_in[2];
    float* out           = (float*)d_out;

    const size_t need = (size_t)BB * NVV * HW * CC * sizeof(float);  // 60.8 MB
    if (ws_size >= need) {
        float* ft = (float*)d_ws;
        dim3 gA(HW / 64, BB * NVV, 1);                 // 464 x 8
        transpose_kernel<<<gA, 256, 0, stream>>>(feats, ft);
        bev_sample_kernel<<<4096, 256, 0, stream>>>(ft, l2c, cam2img, out);
    } else {
        dim3 grid(1024, CC / CG, 1);
        bev_fuse_kernel<<<grid, 256, 0, stream>>>(feats, l2c, cam2img, out);
    }
}

// Round 10
// 138.778 us; speedup vs baseline: 2.1780x; 1.0339x over previous
//
#include <hip/hip_runtime.h>
#include <hip/hip_fp16.h>

// MultiViewBEVFusionUnified — two-kernel plan (fp16 intermediate):
//  A) transpose feats [8][C=64][HW] fp32 -> ws [8][HW][C] fp16 (channel-last)
//  B) per block: 64 voxels; phase1 = 64 vox x 4 views projections -> LDS;
//     phase2 = wave-per-16-voxels, lane=(channel-pair, corner-half),
//     paired-corner half2 gathers (256B/wave/row); shfl_xor(32) combine;
//     LDS transpose -> coalesced output stores.
#define BB   2
#define NVV  4
#define CC   64
#define HFF  128
#define WFF  232
#define HW   (HFF*WFF)        // 29696
#define EPSV 1e-5f

// ---------------- Kernel A: channel-last transpose fp32->fp16 ----------------
__global__ __launch_bounds__(256) void transpose_kernel(
    const float* __restrict__ feats, __half* __restrict__ ft)
{
    __shared__ float lds[64][65];
    const int t   = threadIdx.x;
    const int hw0 = blockIdx.x * 64;
    const size_t sbase = (size_t)blockIdx.y * (CC * HW);
    const int l16 = t & 15, g16 = t >> 4;

    // load: c = g16 + 16r, hw = 4*l16 .. +3 (wave: 4x256B contiguous segments)
#pragma unroll
    for (int r = 0; r < 4; ++r) {
        const int c = g16 + 16 * r;
        const float4 v = *(const float4*)(feats + sbase + (size_t)c * HW + hw0 + 4 * l16);
        lds[c][4*l16 + 0] = v.x;
        lds[c][4*l16 + 1] = v.y;
        lds[c][4*l16 + 2] = v.z;
        lds[c][4*l16 + 3] = v.w;
    }
    __syncthreads();
    // store fp16: thread covers channels 4*l16..+3 at hw = g16 + 16r
    // wave writes 512B contiguous per r
#pragma unroll
    for (int r = 0; r < 4; ++r) {
        const int hw = g16 + 16 * r;
        union { __half2 h[2]; uint2 u; } pk;
        pk.h[0] = __floats2half2_rn(lds[4*l16 + 0][hw], lds[4*l16 + 1][hw]);
        pk.h[1] = __floats2half2_rn(lds[4*l16 + 2][hw], lds[4*l16 + 3][hw]);
        *(uint2*)(ft + sbase + (size_t)(hw0 + hw) * CC + 4 * l16) = pk.u;
    }
}

// ---------------- Kernel B: project + paired-corner fp16 gather + fuse ----------------
__global__ __launch_bounds__(256) void bev_sample_kernel(
    const __half* __restrict__ ft,      // [8][HW][64] channel-last fp16
    const float* __restrict__ l2c,      // [B,NV,4,4]
    const float* __restrict__ cam2img,  // [B,NV,3,3]
    float* __restrict__ out)            // [B,C,NX,NY,NZ]
{
    __shared__ __align__(16) char smem[64 * 66 * 4];   // 16896 B
    float4* s_w   = (float4*)smem;                 // [4][64] pair weights (4KB)
    int2*   s_off = (int2*)(smem + 4096);          // [4][64] row offsets  (2KB)
    int*    s_fl  = (int*)(smem + 6144);           // [64] packed valid bytes
    float*  s_t   = (float*)smem;                  // [64][66] out transpose (aliases)

    const int t   = threadIdx.x;
    const int bid = blockIdx.x;
    const int b   = bid >> 11;
    const int rem = bid & 2047;
    const int xi  = rem >> 4;
    const int yz0 = (rem & 15) << 6;

    // ---- phase 1: projections; thread = (view v = t>>6, voxel j = t&63)
    {
        const int v = t >> 6, j = t & 63;
        const int yzi = yz0 + j;
        const int yi = yzi >> 3, zi = yzi & 7;
        const float X = -25.6f + 0.4f * ((float)xi + 0.5f);
        const float Y = -25.6f + 0.4f * ((float)yi + 0.5f);
        const float Z = -1.0f  + 0.5f * ((float)zi + 0.5f);

        const float* M = l2c + ((b * NVV + v) << 4);
        const float* K = cam2img + (b * NVV + v) * 9;
        const float cx = fmaf(M[0], X, fmaf(M[1], Y, fmaf(M[2],  Z, M[3])));
        const float cy = fmaf(M[4], X, fmaf(M[5], Y, fmaf(M[6],  Z, M[7])));
        const float cz = fmaf(M[8], X, fmaf(M[9], Y, fmaf(M[10], Z, M[11])));
        const float u = fmaf(K[0], cx, fmaf(K[1], cy, K[2] * cz));
        const float w = fmaf(K[3], cx, fmaf(K[4], cy, K[5] * cz));
        const float zc = fmaxf(cz, EPSV);
        const float rz = 1.f / zc;
        const float px = u * rz, py = w * rz;

        const bool valid = (cz > EPSV) && (px >= 0.f) && (px < (float)WFF)
                         && (py >= 0.f) && (py < (float)HFF);

        // bilinear (align_corners=False): sample at (px-0.5, py-0.5)
        const float xf = px - 0.5f, yf = py - 0.5f;
        const float x0f = floorf(xf), y0f = floorf(yf);
        const float wx = xf - x0f, wy = yf - y0f;
        const int x0 = (int)x0f, y0 = (int)y0f;   // valid => x0 in [-1,231], y0 in [-1,127]
        const int y1 = y0 + 1;

        // pair base bx: loaded pixels are (bx, bx+1); remap corner weights onto them
        const int bx = min(max(x0, 0), WFF - 2);
        float wLx, wHx;
        if (x0 < 0)            { wLx = wx;       wHx = 0.f; }       // corner1 at x=0 is L
        else if (x0 >= WFF-1)  { wLx = 0.f;      wHx = 1.f - wx; }  // corner0 at x=231 is H
        else                   { wLx = 1.f - wx; wHx = wx; }

        const float ay0 = (y0 >= 0)      ? (1.f - wy) : 0.f;
        const float ay1 = (y1 <= HFF-1)  ? wy         : 0.f;
        const int y0c = max(y0, 0);
        const int y1c = min(y1, HFF - 1);

        float4 wt;
        wt.x = wLx * ay0; wt.y = wHx * ay0;   // row y0: (L,H)
        wt.z = wLx * ay1; wt.w = wHx * ay1;   // row y1: (L,H)
        int2 off;
        off.x = y0c * WFF + bx;
        off.y = y1c * WFF + bx;

        s_w  [v*64 + j] = wt;
        s_off[v*64 + j] = off;
        ((char*)(smem + 6144))[j*4 + v] = valid ? 1 : 0;
    }
    __syncthreads();

    // ---- phase 2: gather; wave wv owns voxels wv*16..+15
    // lane l<32: pixel L, channels {2l,2l+1}; lane l>=32: pixel H, channels {2(l-32),..}
    const int wv = t >> 6, lane = t & 63;
    const int half = lane >> 5;
    float2 acc[16];
#pragma unroll
    for (int k = 0; k < 16; ++k) acc[k] = make_float2(0.f, 0.f);

    const __half* fsl = ft + (size_t)(b * NVV) * (HW * CC);
#pragma unroll
    for (int k = 0; k < 16; ++k) {
        const int j = wv*16 + k;
        const int flags = s_fl[j];                       // broadcast
        if (flags) {                                     // wave-uniform
            const int cnt = (flags & 1) + ((flags >> 8) & 1)
                          + ((flags >> 16) & 1) + ((flags >> 24) & 1);
            float ax = 0.f, ay = 0.f;
#pragma unroll
            for (int v = 0; v < NVV; ++v) {
                if ((flags >> (8*v)) & 1) {              // wave-uniform
                    const int2   off = s_off[v*64 + j];  // broadcast
                    const float4 wt  = s_w  [v*64 + j];  // broadcast
                    const __half* p0 = fsl + (size_t)v * (HW * CC);
                    // 256B pair loads: rows off.x / off.y, 128 halves each
                    const __half2 h0 = *(const __half2*)(p0 + (size_t)off.x * CC + 2*lane);
                    const __half2 h1 = *(const __half2*)(p0 + (size_t)off.y * CC + 2*lane);
                    const float2 f0 = __half22float2(h0);
                    const float2 f1 = __half22float2(h1);
                    const float wa = half ? wt.y : wt.x;
                    const float wb = half ? wt.w : wt.z;
                    ax = fmaf(f0.x, wa, ax); ay = fmaf(f0.y, wa, ay);
                    ax = fmaf(f1.x, wb, ax); ay = fmaf(f1.y, wb, ay);
                }
            }
            const float scale = (cnt <= 1) ? 1.f : (cnt == 2) ? 0.5f
                              : (cnt == 3) ? (1.f/3.f) : 0.25f;
            acc[k].x = ax * scale;
            acc[k].y = ay * scale;
        }
    }
    __syncthreads();   // phase-2 LDS reads done before aliasing s_t

    // ---- combine corner halves, write transposed to LDS
    const int m2 = (lane & 31) * 2;
#pragma unroll
    for (int k = 0; k < 16; ++k) {
        const float sx = acc[k].x + __shfl_xor(acc[k].x, 32);
        const float sy = acc[k].y + __shfl_xor(acc[k].y, 32);
        if ((k >> 3) == half) {   // half0 writes k=0..7, half1 writes k=8..15
            float2* dst = (float2*)&s_t[(wv*16 + k)*66 + m2];
            *dst = make_float2(sx, sy);
        }
    }
    __syncthreads();

    // ---- coalesced output: lane = voxel, loop channels
    const int jv = t & 63, cr = t >> 6;
    float* ob = out + (size_t)b * (CC * 131072) + (size_t)xi * 1024 + yz0;
#pragma unroll
    for (int r = 0; r < 16; ++r) {
        const int c2 = cr + 4*r;
        ob[(size_t)c2 * 131072 + jv] = s_t[jv*66 + c2];
    }
}

// ---------------- Fallback (round-4 kernel) if ws too small ----------------
#define CG 16
__global__ __launch_bounds__(256) void bev_fuse_kernel(
    const float* __restrict__ feats, const float* __restrict__ l2c,
    const float* __restrict__ cam2img, float* __restrict__ out)
{
    const int tid = blockIdx.x * 256 + threadIdx.x;
    const int b   = tid >> 17;
    const int rem = tid & 131071;
    const int xi  = rem >> 10;
    const int yzi = rem & 1023;
    const int yi  = yzi >> 3;
    const int zi  = yzi & 7;
    const int c0  = blockIdx.y * CG;

    const float X = -25.6f + 0.4f * ((float)xi + 0.5f);
    const float Y = -25.6f + 0.4f * ((float)yi + 0.5f);
    const float Z = -1.0f  + 0.5f * ((float)zi + 0.5f);

    float acc[CG];
#pragma unroll
    for (int c = 0; c < CG; ++c) acc[c] = 0.f;
    float cnt = 0.f;

    for (int v = 0; v < NVV; ++v) {
        const float* M = l2c + ((b * NVV + v) << 4);
        const float* K = cam2img + (b * NVV + v) * 9;
        const float cx = fmaf(M[0], X, fmaf(M[1], Y, fmaf(M[2],  Z, M[3])));
        const float cy = fmaf(M[4], X, fmaf(M[5], Y, fmaf(M[6],  Z, M[7])));
        const float cz = fmaf(M[8], X, fmaf(M[9], Y, fmaf(M[10], Z, M[11])));
        const float u = fmaf(K[0], cx, fmaf(K[1], cy, K[2] * cz));
        const float w = fmaf(K[3], cx, fmaf(K[4], cy, K[5] * cz));
        const float zc = fmaxf(cz, EPSV);
        const float rz = 1.f / zc;
        const float px = u * rz, py = w * rz;
        const bool valid = (cz > EPSV) && (px >= 0.f) && (px < (float)WFF)
                         && (py >= 0.f) && (py < (float)HFF);
        if (!valid) continue;
        cnt += 1.f;
        const float xf = px - 0.5f, yf = py - 0.5f;
        const float x0f = floorf(xf), y0f = floorf(yf);
        const float wx = xf - x0f, wy = yf - y0f;
        const int x0 = (int)x0f, y0 = (int)y0f;
        const int x1 = x0 + 1, y1 = y0 + 1;
        const bool bx0 = (x0 >= 0) & (x0 < WFF);
        const bool bx1 = (x1 >= 0) & (x1 < WFF);
        const bool by0 = (y0 >= 0) & (y0 < HFF);
        const bool by1 = (y1 >= 0) & (y1 < HFF);
        const float w00 = (bx0 && by0) ? (1.f - wx) * (1.f - wy) : 0.f;
        const float w01 = (bx1 && by0) ? wx * (1.f - wy)         : 0.f;
        const float w10 = (bx0 && by1) ? (1.f - wx) * wy         : 0.f;
        const float w11 = (bx1 && by1) ? wx * wy                 : 0.f;
        const int x0c = min(max(x0,0),WFF-1), x1c = min(max(x1,0),WFF-1);
        const int y0c = min(max(y0,0),HFF-1), y1c = min(max(y1,0),HFF-1);
        const int o00 = y0c*WFF+x0c, o01 = y0c*WFF+x1c;
        const int o10 = y1c*WFF+x0c, o11 = y1c*WFF+x1c;
        const float* fb = feats + (size_t)(b*NVV+v)*(CC*HW) + (size_t)c0*HW;
#pragma unroll
        for (int c = 0; c < CG; ++c) {
            const float* fc = fb + c * HW;
            float a = acc[c];
            a = fmaf(fc[o00], w00, a);
            a = fmaf(fc[o01], w01, a);
            a = fmaf(fc[o10], w10, a);
            a = fmaf(fc[o11], w11, a);
            acc[c] = a;
        }
    }
    const float scale = 1.f / fmaxf(cnt, 1.f);
    float* ob = out + (size_t)b*(CC*131072) + (size_t)c0*131072 + xi*1024 + yzi;
#pragma unroll
    for (int c = 0; c < CG; ++c)
        ob[(size_t)c * 131072] = acc[c] * scale;
}

extern "C" void kernel_launch(void* const* d_in, const int* in_sizes, int n_in,
                              void* d_out, int out_size, void* d_ws, size_t ws_size,
                              hipStream_t stream) {
    const float* feats   = (const float*)d_in[0];
    const float* l2c     = (const float*)d_in[1];
    const float* cam2img = (const float*)d_in[2];
    float* out           = (float*)d_out;

    const size_t need = (size_t)BB * NVV * HW * CC * sizeof(__half);  // 30.4 MB
    if (ws_size >= need) {
        __half* ft = (__half*)d_ws;
        dim3 gA(HW / 64, BB * NVV, 1);                 // 464 x 8
        transpose_kernel<<<gA, 256, 0, stream>>>(feats, ft);
        bev_sample_kernel<<<4096, 256, 0, stream>>>(ft, l2c, cam2img, out);
    } else {
        dim3 grid(1024, CC / CG, 1);
        bev_fuse_kernel<<<grid, 256, 0, stream>>>(feats, l2c, cam2img, out);
    }
}